// Round 1
// baseline (498.992 us; speedup 1.0000x reference)
//
#include <hip/hip_runtime.h>

#define NN 50000
#define NE 600000
#define DD 128
#define NH 4
#define ET (NE + NN)
#define NEG_SLOPE 0.2f

// ---------------- CSR build ----------------

__global__ void __launch_bounds__(256) init_counts_k(int* __restrict__ counts) {
    int i = blockIdx.x * 256 + threadIdx.x;
    if (i < NN) counts[i] = 1;  // self-loop contributes 1 per node
}

__global__ void __launch_bounds__(256) count_k(const int* __restrict__ dst, int* __restrict__ counts) {
    int e = blockIdx.x * 256 + threadIdx.x;
    if (e < NE) atomicAdd(&counts[dst[e]], 1);
}

// single-block exclusive scan over NN counts -> offsets[NN+1]
__global__ void __launch_bounds__(1024) scan_k(const int* __restrict__ counts, int* __restrict__ offsets) {
    __shared__ int part[1024];
    int tid = threadIdx.x;
    const int chunk = (NN + 1023) / 1024;
    int start = tid * chunk;
    int end = min(start + chunk, NN);
    int s = 0;
    for (int i = start; i < end; ++i) s += counts[i];
    part[tid] = s;
    __syncthreads();
    for (int off = 1; off < 1024; off <<= 1) {
        int v = (tid >= off) ? part[tid - off] : 0;
        __syncthreads();
        part[tid] += v;
        __syncthreads();
    }
    int run = (tid == 0) ? 0 : part[tid - 1];
    for (int i = start; i < end; ++i) {
        offsets[i] = run;
        run += counts[i];
    }
    if (start < NN && end == NN) offsets[NN] = run;
}

__global__ void __launch_bounds__(256) cursor_k(const int* __restrict__ offsets, int* __restrict__ cursor) {
    int i = blockIdx.x * 256 + threadIdx.x;
    if (i < NN) cursor[i] = offsets[i];
}

__global__ void __launch_bounds__(256) scatter_k(const int* __restrict__ src, const int* __restrict__ dst,
                                                 int* __restrict__ cursor, int* __restrict__ esrc) {
    int e = blockIdx.x * 256 + threadIdx.x;
    if (e < NE) {
        int d = dst[e];
        int pos = atomicAdd(&cursor[d], 1);
        esrc[pos] = src[e];
    } else if (e < ET) {
        int n = e - NE;
        int pos = atomicAdd(&cursor[n], 1);
        esrc[pos] = n;  // self loop: src == dst == n
    }
}

// ---------------- dual GEMM: h = x@W, skip = x@Wskip ----------------
// 16 rows per block, 256 threads: thread (half, col) computes 8 rows x 1 col for both outputs.

__global__ void __launch_bounds__(256) gemm2_k(const float* __restrict__ x, const float* __restrict__ W,
                                               const float* __restrict__ Ws,
                                               float* __restrict__ h, float* __restrict__ skip) {
    __shared__ __align__(16) float xs[16][DD];
    int row0 = blockIdx.x * 16;
    int tid = threadIdx.x;
    // load 16 rows of x (2048 floats) as float4
    for (int i = tid; i < 16 * DD / 4; i += 256) {
        int idx = i * 4;
        *(float4*)&xs[idx >> 7][idx & 127] = *(const float4*)&x[(long)(row0 + (idx >> 7)) * DD + (idx & 127)];
    }
    __syncthreads();
    int col = tid & 127;
    int rbase = (tid >> 7) * 8;
    float acch[8] = {0, 0, 0, 0, 0, 0, 0, 0};
    float accs[8] = {0, 0, 0, 0, 0, 0, 0, 0};
    for (int k = 0; k < DD; k += 4) {
        float w[4], v[4];
#pragma unroll
        for (int u = 0; u < 4; ++u) {
            w[u] = W[(k + u) * DD + col];
            v[u] = Ws[(k + u) * DD + col];
        }
#pragma unroll
        for (int r = 0; r < 8; ++r) {
            float4 xv = *(const float4*)&xs[rbase + r][k];
            acch[r] = fmaf(xv.x, w[0], fmaf(xv.y, w[1], fmaf(xv.z, w[2], fmaf(xv.w, w[3], acch[r]))));
            accs[r] = fmaf(xv.x, v[0], fmaf(xv.y, v[1], fmaf(xv.z, v[2], fmaf(xv.w, v[3], accs[r]))));
        }
    }
#pragma unroll
    for (int r = 0; r < 8; ++r) {
        long o = (long)(row0 + rbase + r) * DD + col;
        h[o] = acch[r];
        skip[o] = accs[r];
    }
}

// ---------------- per-node attention coefficients ----------------
// asrc[n,h] = dot(h[n, h*32 : h*32+32], a_src[h]); same for adst

__global__ void __launch_bounds__(256) att_k(const float* __restrict__ h,
                                             const float* __restrict__ a_src, const float* __restrict__ a_dst,
                                             float* __restrict__ asrc, float* __restrict__ adst) {
    int idx = blockIdx.x * 256 + threadIdx.x;
    if (idx >= NN * NH) return;
    int n = idx >> 2, hh = idx & 3;
    const float* hp = h + (long)n * DD + hh * 32;
    const float* s1 = a_src + hh * 32;
    const float* s2 = a_dst + hh * 32;
    float d1 = 0.f, d2 = 0.f;
#pragma unroll
    for (int c = 0; c < 32; ++c) {
        float v = hp[c];
        d1 = fmaf(v, s1[c], d1);
        d2 = fmaf(v, s2[c], d2);
    }
    asrc[idx] = d1;
    adst[idx] = d2;
}

// ---------------- aggregate: segment softmax + weighted sum + skip + elu ----------------
// one wave (64 threads) per node; thread t owns channels t and t+64.

__global__ void __launch_bounds__(64) aggregate_k(const float* __restrict__ h, const float* __restrict__ skip,
                                                  const float* __restrict__ asrc, const float* __restrict__ adst,
                                                  const int* __restrict__ offsets, const int* __restrict__ esrc,
                                                  const float* __restrict__ bias, float* __restrict__ out) {
    int n = blockIdx.x;
    int lane = threadIdx.x;
    int beg = offsets[n];
    int end = offsets[n + 1];

    float ad0 = adst[n * 4 + 0], ad1 = adst[n * 4 + 1], ad2 = adst[n * 4 + 2], ad3 = adst[n * 4 + 3];

    // pass 1: per-head max over edges (strided across lanes, wave-reduced)
    float mx0 = -1e30f, mx1 = -1e30f, mx2 = -1e30f, mx3 = -1e30f;
    for (int j = beg + lane; j < end; j += 64) {
        int s = esrc[j];
        float a0 = asrc[s * 4 + 0] + ad0; a0 = a0 > 0.f ? a0 : NEG_SLOPE * a0;
        float a1 = asrc[s * 4 + 1] + ad1; a1 = a1 > 0.f ? a1 : NEG_SLOPE * a1;
        float a2 = asrc[s * 4 + 2] + ad2; a2 = a2 > 0.f ? a2 : NEG_SLOPE * a2;
        float a3 = asrc[s * 4 + 3] + ad3; a3 = a3 > 0.f ? a3 : NEG_SLOPE * a3;
        mx0 = fmaxf(mx0, a0); mx1 = fmaxf(mx1, a1); mx2 = fmaxf(mx2, a2); mx3 = fmaxf(mx3, a3);
    }
#pragma unroll
    for (int off = 32; off > 0; off >>= 1) {
        mx0 = fmaxf(mx0, __shfl_xor(mx0, off));
        mx1 = fmaxf(mx1, __shfl_xor(mx1, off));
        mx2 = fmaxf(mx2, __shfl_xor(mx2, off));
        mx3 = fmaxf(mx3, __shfl_xor(mx3, off));
    }

    // pass 2: every lane walks all edges; accumulates its 2 channels + the per-head denom
    int c0 = lane, c1 = lane + 64;
    int h0 = c0 >> 5, h1 = c1 >> 5;              // h0 in {0,1}, h1 in {2,3}
    float adh0 = (h0 == 0) ? ad0 : ad1;
    float adh1 = (h1 == 2) ? ad2 : ad3;
    float mh0 = (h0 == 0) ? mx0 : mx1;
    float mh1 = (h1 == 2) ? mx2 : mx3;

    float acc0 = 0.f, acc1 = 0.f, den0 = 0.f, den1 = 0.f;
    for (int j = beg; j < end; ++j) {
        int s = esrc[j];
        float e0 = asrc[s * 4 + h0] + adh0; e0 = e0 > 0.f ? e0 : NEG_SLOPE * e0;
        float e1 = asrc[s * 4 + h1] + adh1; e1 = e1 > 0.f ? e1 : NEG_SLOPE * e1;
        float w0 = __expf(e0 - mh0);
        float w1 = __expf(e1 - mh1);
        den0 += w0; den1 += w1;
        const float* hp = h + (long)s * DD;
        acc0 = fmaf(w0, hp[c0], acc0);
        acc1 = fmaf(w1, hp[c1], acc1);
    }
    float inv0 = 1.f / (den0 + 1e-16f);
    float inv1 = 1.f / (den1 + 1e-16f);

    long o = (long)n * DD;
    float o0 = acc0 * inv0 + bias[c0] + skip[o + c0];
    float o1 = acc1 * inv1 + bias[c1] + skip[o + c1];
    o0 = o0 > 0.f ? o0 : expm1f(o0);
    o1 = o1 > 0.f ? o1 : expm1f(o1);
    out[o + c0] = o0;
    out[o + c1] = o1;
}

// ---------------- launch ----------------

extern "C" void kernel_launch(void* const* d_in, const int* in_sizes, int n_in,
                              void* d_out, int out_size, void* d_ws, size_t ws_size,
                              hipStream_t stream) {
    const float* x     = (const float*)d_in[0];
    const int* eidx    = (const int*)d_in[1];
    const float* W1    = (const float*)d_in[2];
    const float* as1   = (const float*)d_in[3];
    const float* ad1   = (const float*)d_in[4];
    const float* b1    = (const float*)d_in[5];
    const float* Ws1   = (const float*)d_in[6];
    const float* W2    = (const float*)d_in[7];
    const float* as2   = (const float*)d_in[8];
    const float* ad2   = (const float*)d_in[9];
    const float* b2    = (const float*)d_in[10];
    const float* Ws2   = (const float*)d_in[11];
    float* out = (float*)d_out;

    const int* e_src = eidx;          // edge_index[0]
    const int* e_dst = eidx + NE;     // edge_index[1]

    char* p = (char*)d_ws;
    float* h    = (float*)p; p += (size_t)NN * DD * 4;
    float* skip = (float*)p; p += (size_t)NN * DD * 4;
    float* asrc = (float*)p; p += (size_t)NN * NH * 4;
    float* adst = (float*)p; p += (size_t)NN * NH * 4;
    int* counts  = (int*)p; p += (size_t)NN * 4;
    int* offsets = (int*)p; p += (size_t)(NN + 1) * 4;
    int* cursor  = (int*)p; p += (size_t)NN * 4;
    int* esrc    = (int*)p; p += (size_t)ET * 4;

    // CSR build (shared by both layers)
    init_counts_k<<<(NN + 255) / 256, 256, 0, stream>>>(counts);
    count_k<<<(NE + 255) / 256, 256, 0, stream>>>(e_dst, counts);
    scan_k<<<1, 1024, 0, stream>>>(counts, offsets);
    cursor_k<<<(NN + 255) / 256, 256, 0, stream>>>(offsets, cursor);
    scatter_k<<<(ET + 255) / 256, 256, 0, stream>>>(e_src, e_dst, cursor, esrc);

    // layer 1 (write activation into d_out as temp)
    gemm2_k<<<NN / 16, 256, 0, stream>>>(x, W1, Ws1, h, skip);
    att_k<<<(NN * NH + 255) / 256, 256, 0, stream>>>(h, as1, ad1, asrc, adst);
    aggregate_k<<<NN, 64, 0, stream>>>(h, skip, asrc, adst, offsets, esrc, b1, out);

    // layer 2 (reads d_out as input, final result overwrites d_out)
    gemm2_k<<<NN / 16, 256, 0, stream>>>(out, W2, Ws2, h, skip);
    att_k<<<(NN * NH + 255) / 256, 256, 0, stream>>>(h, as2, ad2, asrc, adst);
    aggregate_k<<<NN, 64, 0, stream>>>(h, skip, asrc, adst, offsets, esrc, b2, out);
}

// Round 2
// 422.465 us; speedup vs baseline: 1.1811x; 1.1811x over previous
//
#include <hip/hip_runtime.h>
#include <hip/hip_bf16.h>

#define NN 50000
#define NE 600000
#define DD 128
#define NH 4
#define ET (NE + NN)
#define NEG_SLOPE 0.2f
#define NB 196  // ceil(NN/256) scan blocks

typedef __attribute__((ext_vector_type(8))) short short8;
typedef __attribute__((ext_vector_type(4))) float f32x4;

__device__ __forceinline__ float bf2f(unsigned short u) {
    union { unsigned int i; float f; } c; c.i = ((unsigned int)u) << 16; return c.f;
}
__device__ __forceinline__ unsigned short f2bf(float f) {
    union { float f; unsigned int i; } c; c.f = f;
    unsigned int r = c.i + 0x7FFF + ((c.i >> 16) & 1);  // round-to-nearest-even
    return (unsigned short)(r >> 16);
}

// ---------------- prep: W->bf16 transposed [col][k]; counts=1 (self-loop) ----------------

__global__ void __launch_bounds__(256) prep_k(const float* __restrict__ W1, const float* __restrict__ Ws1,
                                              const float* __restrict__ W2, const float* __restrict__ Ws2,
                                              unsigned short* __restrict__ Wt, int* __restrict__ counts) {
    int idx = blockIdx.x * 256 + threadIdx.x;  // 0..65535
    int mat = idx >> 14;
    int r = idx & 16383;
    int k = r >> 7;
    int col = r & 127;
    const float* Wsrc = (mat == 0) ? W1 : (mat == 1) ? Ws1 : (mat == 2) ? W2 : Ws2;
    Wt[mat * 16384 + col * DD + k] = f2bf(Wsrc[k * DD + col]);
    if (idx < NN) counts[idx] = 1;
}

__global__ void __launch_bounds__(256) count_k(const int* __restrict__ dst, int* __restrict__ counts) {
    int e = blockIdx.x * 256 + threadIdx.x;
    if (e < NE) atomicAdd(&counts[dst[e]], 1);
}

// ---------------- two-level scan ----------------

__global__ void __launch_bounds__(256) partial_k(const int* __restrict__ counts, int* __restrict__ bsum) {
    __shared__ int tmp[256];
    int t = blockIdx.x * 256 + threadIdx.x;
    int v = (t < NN) ? counts[t] : 0;
    tmp[threadIdx.x] = v;
    __syncthreads();
    for (int off = 128; off > 0; off >>= 1) {
        if (threadIdx.x < off) tmp[threadIdx.x] += tmp[threadIdx.x + off];
        __syncthreads();
    }
    if (threadIdx.x == 0) bsum[blockIdx.x] = tmp[0];
}

__global__ void __launch_bounds__(256) scanb_k(const int* __restrict__ bsum, int* __restrict__ boff) {
    __shared__ int tmp[256];
    int tid = threadIdx.x;
    int v = (tid < NB) ? bsum[tid] : 0;
    tmp[tid] = v;
    __syncthreads();
    for (int off = 1; off < 256; off <<= 1) {
        int u = (tid >= off) ? tmp[tid - off] : 0;
        __syncthreads();
        tmp[tid] += u;
        __syncthreads();
    }
    if (tid < NB) boff[tid] = tmp[tid] - v;  // exclusive
}

__global__ void __launch_bounds__(256) offsets_k(const int* __restrict__ counts, const int* __restrict__ boff,
                                                 int* __restrict__ offsets, int* __restrict__ cursor) {
    __shared__ int tmp[256];
    int b = blockIdx.x, tid = threadIdx.x;
    int t = b * 256 + tid;
    int v = (t < NN) ? counts[t] : 0;
    tmp[tid] = v;
    __syncthreads();
    for (int off = 1; off < 256; off <<= 1) {
        int u = (tid >= off) ? tmp[tid - off] : 0;
        __syncthreads();
        tmp[tid] += u;
        __syncthreads();
    }
    if (t < NN) {
        int o = boff[b] + tmp[tid] - v;
        offsets[t] = o;
        cursor[t] = o;
    }
    if (b == 0 && tid == 0) offsets[NN] = ET;
}

__global__ void __launch_bounds__(256) scatter_k(const int* __restrict__ src, const int* __restrict__ dst,
                                                 int* __restrict__ cursor, int* __restrict__ esrc) {
    int e = blockIdx.x * 256 + threadIdx.x;
    if (e < NE) {
        int pos = atomicAdd(&cursor[dst[e]], 1);
        esrc[pos] = src[e];
    } else if (e < ET) {
        int n = e - NE;
        int pos = atomicAdd(&cursor[n], 1);
        esrc[pos] = n;
    }
}

// ---------------- MFMA dual GEMM: h2 = bf16(x@W), skip = x@Wskip ----------------
// 64 rows/block, 4 waves, wave w: rows w*16..w*16+15 x 128 cols (8 col-tiles).
// xs: 64 rows x 128 bf16, 16B-chunk XOR swizzle (chunk ^= row&7) for conflict-free ds_read_b128.

template <bool F32IN>
__global__ void __launch_bounds__(256) gemm2_k(const void* __restrict__ xin,
                                               const unsigned short* __restrict__ Wt,
                                               const unsigned short* __restrict__ Wst,
                                               unsigned short* __restrict__ h2, float* __restrict__ skip) {
    __shared__ __align__(16) unsigned char xs[64 * 256];
    int row0 = blockIdx.x * 64;
    int tid = threadIdx.x;
#pragma unroll
    for (int i = 0; i < 4; ++i) {
        int cid = i * 256 + tid;        // 16B chunk id, 0..1023
        int row = cid >> 4, c = cid & 15;
        int rsrc = row0 + row;
        if (rsrc >= NN) rsrc = NN - 1;  // clamp (stores guarded)
        uint4 pk;
        if (F32IN) {
            const float* xp = (const float*)xin + (size_t)rsrc * DD + c * 8;
            float4 u0 = *(const float4*)xp;
            float4 u1 = *(const float4*)(xp + 4);
            pk.x = (unsigned)f2bf(u0.x) | ((unsigned)f2bf(u0.y) << 16);
            pk.y = (unsigned)f2bf(u0.z) | ((unsigned)f2bf(u0.w) << 16);
            pk.z = (unsigned)f2bf(u1.x) | ((unsigned)f2bf(u1.y) << 16);
            pk.w = (unsigned)f2bf(u1.z) | ((unsigned)f2bf(u1.w) << 16);
        } else {
            pk = *(const uint4*)((const unsigned short*)xin + (size_t)rsrc * DD + c * 8);
        }
        int cs = c ^ (row & 7);
        *(uint4*)&xs[row * 256 + cs * 16] = pk;
    }
    __syncthreads();

    int w = tid >> 6, l = tid & 63;
    int lrow = l & 15, lk = l >> 4;  // A row / k-group
    int srow = w * 16 + lrow;
    f32x4 zero = {0.f, 0.f, 0.f, 0.f};
    f32x4 acch[8], accs[8];
#pragma unroll
    for (int t = 0; t < 8; ++t) { acch[t] = zero; accs[t] = zero; }

#pragma unroll
    for (int kc = 0; kc < 4; ++kc) {
        int chunk = (kc * 4 + lk) ^ (srow & 7);
        short8 a = *(const short8*)&xs[srow * 256 + chunk * 16];
#pragma unroll
        for (int t = 0; t < 8; ++t) {
            short8 b = *(const short8*)(Wt + (size_t)(t * 16 + lrow) * DD + kc * 32 + lk * 8);
            acch[t] = __builtin_amdgcn_mfma_f32_16x16x32_bf16(a, b, acch[t], 0, 0, 0);
            short8 bs = *(const short8*)(Wst + (size_t)(t * 16 + lrow) * DD + kc * 32 + lk * 8);
            accs[t] = __builtin_amdgcn_mfma_f32_16x16x32_bf16(a, bs, accs[t], 0, 0, 0);
        }
    }
    // D: col = lane&15, row = (lane>>4)*4 + reg
#pragma unroll
    for (int t = 0; t < 8; ++t) {
#pragma unroll
        for (int q = 0; q < 4; ++q) {
            int grow = row0 + w * 16 + lk * 4 + q;
            if (grow < NN) {
                int col = t * 16 + lrow;
                h2[(size_t)grow * DD + col] = f2bf(acch[t][q]);
                skip[(size_t)grow * DD + col] = accs[t][q];
            }
        }
    }
}

// ---------------- per-node attention coefficients (bf16 h) ----------------

__global__ void __launch_bounds__(256) att_k(const unsigned short* __restrict__ h2,
                                             const float* __restrict__ a_src, const float* __restrict__ a_dst,
                                             float* __restrict__ asrc, float* __restrict__ adst) {
    int idx = blockIdx.x * 256 + threadIdx.x;
    if (idx >= NN * NH) return;
    int hh = idx & 3;
    const unsigned short* hp = h2 + (size_t)(idx >> 2) * DD + hh * 32;
    const float* s1 = a_src + hh * 32;
    const float* s2 = a_dst + hh * 32;
    float d1 = 0.f, d2 = 0.f;
#pragma unroll
    for (int u = 0; u < 4; ++u) {
        uint4 v = *(const uint4*)(hp + u * 8);
        unsigned int ws[4] = {v.x, v.y, v.z, v.w};
#pragma unroll
        for (int j = 0; j < 4; ++j) {
            float f0 = bf2f((unsigned short)(ws[j] & 0xFFFF));
            float f1 = bf2f((unsigned short)(ws[j] >> 16));
            int c = u * 8 + j * 2;
            d1 = fmaf(f0, s1[c], fmaf(f1, s1[c + 1], d1));
            d2 = fmaf(f0, s2[c], fmaf(f1, s2[c + 1], d2));
        }
    }
    asrc[idx] = d1;
    adst[idx] = d2;
}

// ---------------- aggregate: segment softmax + weighted bf16 gather + skip + elu ----------------
// 4 nodes/block (1 wave each); lane owns channels 2*lane, 2*lane+1 (single head per lane).

__global__ void __launch_bounds__(256) aggregate_k(const unsigned short* __restrict__ h2, const float* __restrict__ skip,
                                                   const float* __restrict__ asrc, const float* __restrict__ adst,
                                                   const int* __restrict__ offsets, const int* __restrict__ esrc,
                                                   const float* __restrict__ bias, float* __restrict__ outf,
                                                   unsigned short* __restrict__ outb) {
    int n = blockIdx.x * 4 + (threadIdx.x >> 6);
    int lane = threadIdx.x & 63;
    int beg = offsets[n], end = offsets[n + 1];
    float4 adv = *(const float4*)&adst[n * 4];

    // pass 1: per-head max (strided lanes, wave reduce)
    float mx0 = -1e30f, mx1 = -1e30f, mx2 = -1e30f, mx3 = -1e30f;
    for (int j = beg + lane; j < end; j += 64) {
        int s = esrc[j];
        float4 av = *(const float4*)&asrc[s * 4];
        float a0 = av.x + adv.x; a0 = a0 > 0.f ? a0 : NEG_SLOPE * a0;
        float a1 = av.y + adv.y; a1 = a1 > 0.f ? a1 : NEG_SLOPE * a1;
        float a2 = av.z + adv.z; a2 = a2 > 0.f ? a2 : NEG_SLOPE * a2;
        float a3 = av.w + adv.w; a3 = a3 > 0.f ? a3 : NEG_SLOPE * a3;
        mx0 = fmaxf(mx0, a0); mx1 = fmaxf(mx1, a1);
        mx2 = fmaxf(mx2, a2); mx3 = fmaxf(mx3, a3);
    }
#pragma unroll
    for (int off = 32; off > 0; off >>= 1) {
        mx0 = fmaxf(mx0, __shfl_xor(mx0, off));
        mx1 = fmaxf(mx1, __shfl_xor(mx1, off));
        mx2 = fmaxf(mx2, __shfl_xor(mx2, off));
        mx3 = fmaxf(mx3, __shfl_xor(mx3, off));
    }

    int myh = lane >> 4;  // head of channels 2*lane, 2*lane+1
    float ad_my = (myh == 0) ? adv.x : (myh == 1) ? adv.y : (myh == 2) ? adv.z : adv.w;
    float mh = (myh == 0) ? mx0 : (myh == 1) ? mx1 : (myh == 2) ? mx2 : mx3;
    int c0 = 2 * lane;

    float acc0 = 0.f, acc1 = 0.f, den = 0.f;
    for (int j = beg; j < end; ++j) {
        int s = esrc[j];
        float e = asrc[s * 4 + myh] + ad_my;
        e = e > 0.f ? e : NEG_SLOPE * e;
        float wgt = __expf(e - mh);
        den += wgt;
        unsigned int hv = *(const unsigned int*)&h2[(size_t)s * DD + c0];
        acc0 = fmaf(wgt, bf2f((unsigned short)(hv & 0xFFFF)), acc0);
        acc1 = fmaf(wgt, bf2f((unsigned short)(hv >> 16)), acc1);
    }
    float inv = 1.f / (den + 1e-16f);
    size_t o = (size_t)n * DD;
    float o0 = acc0 * inv + bias[c0] + skip[o + c0];
    float o1 = acc1 * inv + bias[c0 + 1] + skip[o + c0 + 1];
    o0 = o0 > 0.f ? o0 : expm1f(o0);
    o1 = o1 > 0.f ? o1 : expm1f(o1);
    if (outf) { outf[o + c0] = o0; outf[o + c0 + 1] = o1; }
    if (outb) { outb[o + c0] = f2bf(o0); outb[o + c0 + 1] = f2bf(o1); }
}

// ---------------- launch ----------------

extern "C" void kernel_launch(void* const* d_in, const int* in_sizes, int n_in,
                              void* d_out, int out_size, void* d_ws, size_t ws_size,
                              hipStream_t stream) {
    const float* x   = (const float*)d_in[0];
    const int* eidx  = (const int*)d_in[1];
    const float* W1  = (const float*)d_in[2];
    const float* as1 = (const float*)d_in[3];
    const float* ad1 = (const float*)d_in[4];
    const float* b1  = (const float*)d_in[5];
    const float* Ws1 = (const float*)d_in[6];
    const float* W2  = (const float*)d_in[7];
    const float* as2 = (const float*)d_in[8];
    const float* ad2 = (const float*)d_in[9];
    const float* b2  = (const float*)d_in[10];
    const float* Ws2 = (const float*)d_in[11];
    float* out = (float*)d_out;

    const int* e_src = eidx;
    const int* e_dst = eidx + NE;

    char* p = (char*)d_ws;
    unsigned short* h2 = (unsigned short*)p; p += (size_t)NN * DD * 2;
    unsigned short* xb = (unsigned short*)p; p += (size_t)NN * DD * 2;
    float* skip = (float*)p; p += (size_t)NN * DD * 4;
    float* asrc = (float*)p; p += (size_t)NN * NH * 4;
    float* adst = (float*)p; p += (size_t)NN * NH * 4;
    unsigned short* Wt = (unsigned short*)p; p += (size_t)4 * DD * DD * 2;
    int* counts  = (int*)p; p += (size_t)NN * 4;
    int* offsets = (int*)p; p += (size_t)(NN + 1) * 4;
    int* cursor  = (int*)p; p += (size_t)NN * 4;
    int* bsum    = (int*)p; p += 256 * 4;
    int* boff    = (int*)p; p += 256 * 4;
    int* esrc    = (int*)p; p += (size_t)ET * 4;

    const unsigned short* W1t  = Wt;
    const unsigned short* Ws1t = Wt + 16384;
    const unsigned short* W2t  = Wt + 32768;
    const unsigned short* Ws2t = Wt + 49152;

    // CSR build
    prep_k<<<256, 256, 0, stream>>>(W1, Ws1, W2, Ws2, Wt, counts);
    count_k<<<(NE + 255) / 256, 256, 0, stream>>>(e_dst, counts);
    partial_k<<<NB, 256, 0, stream>>>(counts, bsum);
    scanb_k<<<1, 256, 0, stream>>>(bsum, boff);
    offsets_k<<<NB, 256, 0, stream>>>(counts, boff, offsets, cursor);
    scatter_k<<<(ET + 255) / 256, 256, 0, stream>>>(e_src, e_dst, cursor, esrc);

    const int GG = (NN + 63) / 64;  // 782

    // layer 1 (bf16 activation only)
    gemm2_k<true><<<GG, 256, 0, stream>>>(x, W1t, Ws1t, h2, skip);
    att_k<<<(NN * NH + 255) / 256, 256, 0, stream>>>(h2, as1, ad1, asrc, adst);
    aggregate_k<<<NN / 4, 256, 0, stream>>>(h2, skip, asrc, adst, offsets, esrc, b1, nullptr, xb);

    // layer 2 (final f32 output)
    gemm2_k<false><<<GG, 256, 0, stream>>>(xb, W2t, Ws2t, h2, skip);
    att_k<<<(NN * NH + 255) / 256, 256, 0, stream>>>(h2, as2, ad2, asrc, adst);
    aggregate_k<<<NN / 4, 256, 0, stream>>>(h2, skip, asrc, adst, offsets, esrc, b2, out, nullptr);
}

// Round 4
// 318.090 us; speedup vs baseline: 1.5687x; 1.3281x over previous
//
#include <hip/hip_runtime.h>
#include <hip/hip_bf16.h>

#define NN 50000
#define NE 600000
#define DD 128
#define NH 4
#define ET (NE + NN)
#define NEG_SLOPE 0.2f
#define NB 196  // ceil(NN/256) scan blocks

typedef __attribute__((ext_vector_type(8))) short short8;
typedef __attribute__((ext_vector_type(4))) float f32x4;

__device__ __forceinline__ float bf2f(unsigned short u) {
    union { unsigned int i; float f; } c; c.i = ((unsigned int)u) << 16; return c.f;
}
__device__ __forceinline__ unsigned short f2bf(float f) {
    union { float f; unsigned int i; } c; c.f = f;
    unsigned int r = c.i + 0x7FFF + ((c.i >> 16) & 1);  // RNE
    return (unsigned short)(r >> 16);
}

// ---------------- prep: W->bf16 transposed [col][k]; counts=1 (self-loop slot) ----------------

__global__ void __launch_bounds__(256) prep_k(const float* __restrict__ W1, const float* __restrict__ Ws1,
                                              const float* __restrict__ W2, const float* __restrict__ Ws2,
                                              unsigned short* __restrict__ Wt, int* __restrict__ counts) {
    int idx = blockIdx.x * 256 + threadIdx.x;  // 0..65535
    int mat = idx >> 14;
    int r = idx & 16383;
    int k = r >> 7;
    int col = r & 127;
    const float* Wsrc = (mat == 0) ? W1 : (mat == 1) ? Ws1 : (mat == 2) ? W2 : Ws2;
    Wt[mat * 16384 + col * DD + k] = f2bf(Wsrc[k * DD + col]);
    if (idx < NN) counts[idx] = 1;
}

__global__ void __launch_bounds__(256) count_k(const int* __restrict__ dst, int* __restrict__ counts) {
    int e = blockIdx.x * 256 + threadIdx.x;
    if (e < NE) atomicAdd(&counts[dst[e]], 1);
}

// ---------------- two-level scan ----------------

__global__ void __launch_bounds__(256) partial_k(const int* __restrict__ counts, int* __restrict__ bsum) {
    __shared__ int tmp[256];
    int t = blockIdx.x * 256 + threadIdx.x;
    int v = (t < NN) ? counts[t] : 0;
    tmp[threadIdx.x] = v;
    __syncthreads();
    for (int off = 128; off > 0; off >>= 1) {
        if (threadIdx.x < off) tmp[threadIdx.x] += tmp[threadIdx.x + off];
        __syncthreads();
    }
    if (threadIdx.x == 0) bsum[blockIdx.x] = tmp[0];
}

__global__ void __launch_bounds__(256) scanb_k(const int* __restrict__ bsum, int* __restrict__ boff) {
    __shared__ int tmp[256];
    int tid = threadIdx.x;
    int v = (tid < NB) ? bsum[tid] : 0;
    tmp[tid] = v;
    __syncthreads();
    for (int off = 1; off < 256; off <<= 1) {
        int u = (tid >= off) ? tmp[tid - off] : 0;
        __syncthreads();
        tmp[tid] += u;
        __syncthreads();
    }
    if (tid < NB) boff[tid] = tmp[tid] - v;  // exclusive
}

// offsets + cursor + self-loop placement at the last slot of each segment
__global__ void __launch_bounds__(256) offsets_k(const int* __restrict__ counts, const int* __restrict__ boff,
                                                 int* __restrict__ offsets, int* __restrict__ cursor,
                                                 int* __restrict__ esrc) {
    __shared__ int tmp[256];
    int b = blockIdx.x, tid = threadIdx.x;
    int t = b * 256 + tid;
    int v = (t < NN) ? counts[t] : 0;
    tmp[tid] = v;
    __syncthreads();
    for (int off = 1; off < 256; off <<= 1) {
        int u = (tid >= off) ? tmp[tid - off] : 0;
        __syncthreads();
        tmp[tid] += u;
        __syncthreads();
    }
    if (t < NN) {
        int o = boff[b] + tmp[tid] - v;
        offsets[t] = o;
        cursor[t] = o;
        esrc[o + v - 1] = t;  // self loop in the reserved last slot
    }
    if (b == 0 && tid == 0) offsets[NN] = ET;
}

__global__ void __launch_bounds__(256) scatter_k(const int* __restrict__ src, const int* __restrict__ dst,
                                                 int* __restrict__ cursor, int* __restrict__ esrc) {
    int e = blockIdx.x * 256 + threadIdx.x;
    if (e < NE) {
        int pos = atomicAdd(&cursor[dst[e]], 1);
        esrc[pos] = src[e];
    }
}

// ---------------- MFMA dual GEMM + fused attention coefficients ----------------
// 64 rows/block, 4 waves; wave w: rows w*16..+15 x 128 cols (8 col-tiles).
// Epilogue computes nsrc/ndst (per-node att dot products) from the f32 accumulators.

template <bool F32IN>
__global__ void __launch_bounds__(256) gemm2_k(const void* __restrict__ xin,
                                               const unsigned short* __restrict__ Wt,
                                               const unsigned short* __restrict__ Wst,
                                               const float* __restrict__ a_src, const float* __restrict__ a_dst,
                                               unsigned short* __restrict__ h2, unsigned short* __restrict__ skipb,
                                               float* __restrict__ nsrc, float* __restrict__ ndst) {
    __shared__ __align__(16) unsigned char xs[64 * 256];
    int row0 = blockIdx.x * 64;
    int tid = threadIdx.x;
#pragma unroll
    for (int i = 0; i < 4; ++i) {
        int cid = i * 256 + tid;        // 16B chunk id, 0..1023
        int row = cid >> 4, c = cid & 15;
        int rsrc = row0 + row;
        if (rsrc >= NN) rsrc = NN - 1;  // clamp (stores guarded)
        uint4 pk;
        if (F32IN) {
            const float* xp = (const float*)xin + (size_t)rsrc * DD + c * 8;
            float4 u0 = *(const float4*)xp;
            float4 u1 = *(const float4*)(xp + 4);
            pk.x = (unsigned)f2bf(u0.x) | ((unsigned)f2bf(u0.y) << 16);
            pk.y = (unsigned)f2bf(u0.z) | ((unsigned)f2bf(u0.w) << 16);
            pk.z = (unsigned)f2bf(u1.x) | ((unsigned)f2bf(u1.y) << 16);
            pk.w = (unsigned)f2bf(u1.z) | ((unsigned)f2bf(u1.w) << 16);
        } else {
            pk = *(const uint4*)((const unsigned short*)xin + (size_t)rsrc * DD + c * 8);
        }
        int cs = c ^ (row & 7);
        *(uint4*)&xs[row * 256 + cs * 16] = pk;
    }
    __syncthreads();

    int w = tid >> 6, l = tid & 63;
    int lrow = l & 15, lk = l >> 4;
    int srow = w * 16 + lrow;
    f32x4 zero = {0.f, 0.f, 0.f, 0.f};
    f32x4 acch[8], accs[8];
#pragma unroll
    for (int t = 0; t < 8; ++t) { acch[t] = zero; accs[t] = zero; }

#pragma unroll
    for (int kc = 0; kc < 4; ++kc) {
        int chunk = (kc * 4 + lk) ^ (srow & 7);
        short8 a = *(const short8*)&xs[srow * 256 + chunk * 16];
#pragma unroll
        for (int t = 0; t < 8; ++t) {
            short8 b = *(const short8*)(Wt + (size_t)(t * 16 + lrow) * DD + kc * 32 + lk * 8);
            acch[t] = __builtin_amdgcn_mfma_f32_16x16x32_bf16(a, b, acch[t], 0, 0, 0);
            short8 bs = *(const short8*)(Wst + (size_t)(t * 16 + lrow) * DD + kc * 32 + lk * 8);
            accs[t] = __builtin_amdgcn_mfma_f32_16x16x32_bf16(a, bs, accs[t], 0, 0, 0);
        }
    }
    // D: col = lane&15, row = (lane>>4)*4 + reg
#pragma unroll
    for (int t = 0; t < 8; ++t) {
#pragma unroll
        for (int q = 0; q < 4; ++q) {
            int grow = row0 + w * 16 + lk * 4 + q;
            if (grow < NN) {
                int col = t * 16 + lrow;
                h2[(size_t)grow * DD + col] = f2bf(acch[t][q]);
                skipb[(size_t)grow * DD + col] = f2bf(accs[t][q]);
            }
        }
    }

    // fused att: nsrc[row][h] = sum_c h[row][32h+c]*a_src[h][c]  (f32 accs, 16-lane reduce)
    float as_lo[NH], as_hi[NH], ad_lo[NH], ad_hi[NH];
#pragma unroll
    for (int h = 0; h < NH; ++h) {
        as_lo[h] = a_src[h * 32 + lrow];
        as_hi[h] = a_src[h * 32 + 16 + lrow];
        ad_lo[h] = a_dst[h * 32 + lrow];
        ad_hi[h] = a_dst[h * 32 + 16 + lrow];
    }
#pragma unroll
    for (int h = 0; h < NH; ++h) {
#pragma unroll
        for (int q = 0; q < 4; ++q) {
            float ps = acch[2 * h][q] * as_lo[h] + acch[2 * h + 1][q] * as_hi[h];
            float pd = acch[2 * h][q] * ad_lo[h] + acch[2 * h + 1][q] * ad_hi[h];
#pragma unroll
            for (int off = 1; off < 16; off <<= 1) {
                ps += __shfl_xor(ps, off);
                pd += __shfl_xor(pd, off);
            }
            if (lrow == 0) {
                int grow = row0 + w * 16 + lk * 4 + q;
                if (grow < NN) {
                    nsrc[grow * 4 + h] = ps;
                    ndst[grow * 4 + h] = pd;
                }
            }
        }
    }
}

// ---------------- aggregate: single-pass online segment softmax + weighted bf16 gather ----------------
// 4 nodes/block (1 wave each). Lane i: computes weight for (edge-slot i&15, head i>>4);
// owns output channels 2i, 2i+1 (head(2i)=i>>4, same lanes). 16 edges per chunk.

__global__ void __launch_bounds__(256) aggregate_k(const unsigned short* __restrict__ h2,
                                                   const unsigned short* __restrict__ skipb,
                                                   const float* __restrict__ nsrc, const float* __restrict__ ndst,
                                                   const int* __restrict__ offsets, const int* __restrict__ esrc,
                                                   const float* __restrict__ bias, float* __restrict__ outf,
                                                   unsigned short* __restrict__ outb) {
    int n = blockIdx.x * 4 + (threadIdx.x >> 6);
    int i = threadIdx.x & 63;
    int e = i & 15, hc = i >> 4;
    int gbase = i & 48;
    int beg = offsets[n], end = offsets[n + 1];
    float ad = ndst[n * 4 + hc];
    const unsigned int* h2w = (const unsigned int*)h2;

    float m = -1e30f, den = 0.f, acc0 = 0.f, acc1 = 0.f;
    for (int base = beg; base < end; base += 16) {
        int j = base + e;
        int jc = j < end ? j : end - 1;
        int s = esrc[jc];
        float a = nsrc[s * 4 + hc] + ad;
        a = a > 0.f ? a : NEG_SLOPE * a;
        if (j >= end) a = -1e30f;
        // chunk max per head (butterfly over edge-slot bits)
        float cm = a;
        cm = fmaxf(cm, __shfl_xor(cm, 1));
        cm = fmaxf(cm, __shfl_xor(cm, 2));
        cm = fmaxf(cm, __shfl_xor(cm, 4));
        cm = fmaxf(cm, __shfl_xor(cm, 8));
        float mn = fmaxf(m, cm);
        float scale = __expf(m - mn);   // first chunk: exp(-1e30-mn)=0
        float wgt = __expf(a - mn);     // masked lanes: 0
        m = mn;
        float sw = wgt;
        sw += __shfl_xor(sw, 1);
        sw += __shfl_xor(sw, 2);
        sw += __shfl_xor(sw, 4);
        sw += __shfl_xor(sw, 8);
        den = den * scale + sw;
        acc0 *= scale;
        acc1 *= scale;
#pragma unroll
        for (int e2 = 0; e2 < 16; ++e2) {
            int se = __shfl(s, e2);                 // lanes 0..15 hold s for slots 0..15
            float we = __shfl(wgt, gbase + e2);     // weight for (e2, my head)
            unsigned hv = h2w[se * 64 + i];         // 2 bf16 channels
            acc0 = fmaf(we, bf2f((unsigned short)(hv & 0xFFFF)), acc0);
            acc1 = fmaf(we, bf2f((unsigned short)(hv >> 16)), acc1);
        }
    }
    float inv = 1.f / (den + 1e-16f);
    int c0 = 2 * i;
    unsigned sk = ((const unsigned int*)skipb)[n * 64 + i];
    float2 bv = *(const float2*)&bias[c0];
    float o0 = acc0 * inv + bv.x + bf2f((unsigned short)(sk & 0xFFFF));
    float o1 = acc1 * inv + bv.y + bf2f((unsigned short)(sk >> 16));
    o0 = o0 > 0.f ? o0 : expm1f(o0);
    o1 = o1 > 0.f ? o1 : expm1f(o1);
    size_t o = (size_t)n * DD;
    if (outf) { outf[o + c0] = o0; outf[o + c0 + 1] = o1; }
    if (outb) { outb[o + c0] = f2bf(o0); outb[o + c0 + 1] = f2bf(o1); }
}

// ---------------- launch ----------------

extern "C" void kernel_launch(void* const* d_in, const int* in_sizes, int n_in,
                              void* d_out, int out_size, void* d_ws, size_t ws_size,
                              hipStream_t stream) {
    const float* x   = (const float*)d_in[0];
    const int* eidx  = (const int*)d_in[1];
    const float* W1  = (const float*)d_in[2];
    const float* as1 = (const float*)d_in[3];
    const float* ad1 = (const float*)d_in[4];
    const float* b1  = (const float*)d_in[5];
    const float* Ws1 = (const float*)d_in[6];
    const float* W2  = (const float*)d_in[7];
    const float* as2 = (const float*)d_in[8];
    const float* ad2 = (const float*)d_in[9];
    const float* b2  = (const float*)d_in[10];
    const float* Ws2 = (const float*)d_in[11];
    float* out = (float*)d_out;

    const int* e_src = eidx;
    const int* e_dst = eidx + NE;

    char* p = (char*)d_ws;
    unsigned short* h2    = (unsigned short*)p; p += (size_t)NN * DD * 2;
    unsigned short* xb    = (unsigned short*)p; p += (size_t)NN * DD * 2;
    unsigned short* skipb = (unsigned short*)p; p += (size_t)NN * DD * 2;
    float* nsrc = (float*)p; p += (size_t)NN * NH * 4;
    float* ndst = (float*)p; p += (size_t)NN * NH * 4;
    unsigned short* Wt = (unsigned short*)p; p += (size_t)4 * DD * DD * 2;
    int* counts  = (int*)p; p += (size_t)NN * 4;
    int* offsets = (int*)p; p += (size_t)(NN + 1) * 4;
    int* cursor  = (int*)p; p += (size_t)NN * 4;
    int* bsum    = (int*)p; p += 256 * 4;
    int* boff    = (int*)p; p += 256 * 4;
    int* esrc    = (int*)p; p += (size_t)ET * 4;

    const unsigned short* W1t  = Wt;
    const unsigned short* Ws1t = Wt + 16384;
    const unsigned short* W2t  = Wt + 32768;
    const unsigned short* Ws2t = Wt + 49152;

    // CSR build
    prep_k<<<256, 256, 0, stream>>>(W1, Ws1, W2, Ws2, Wt, counts);
    count_k<<<(NE + 255) / 256, 256, 0, stream>>>(e_dst, counts);
    partial_k<<<NB, 256, 0, stream>>>(counts, bsum);
    scanb_k<<<1, 256, 0, stream>>>(bsum, boff);
    offsets_k<<<NB, 256, 0, stream>>>(counts, boff, offsets, cursor, esrc);
    scatter_k<<<(NE + 255) / 256, 256, 0, stream>>>(e_src, e_dst, cursor, esrc);

    const int GG = (NN + 63) / 64;  // 782

    // layer 1
    gemm2_k<true><<<GG, 256, 0, stream>>>(x, W1t, Ws1t, as1, ad1, h2, skipb, nsrc, ndst);
    aggregate_k<<<NN / 4, 256, 0, stream>>>(h2, skipb, nsrc, ndst, offsets, esrc, b1, nullptr, xb);

    // layer 2
    gemm2_k<false><<<GG, 256, 0, stream>>>(xb, W2t, Ws2t, as2, ad2, h2, skipb, nsrc, ndst);
    aggregate_k<<<NN / 4, 256, 0, stream>>>(h2, skipb, nsrc, ndst, offsets, esrc, b2, out, nullptr);
}

// Round 5
// 268.894 us; speedup vs baseline: 1.8557x; 1.1830x over previous
//
#include <hip/hip_runtime.h>
#include <hip/hip_bf16.h>

#define NN 50000
#define NE 600000
#define DD 128
#define NH 4
#define ET (NE + NN)
#define NEG_SLOPE 0.2f
#define NB 196  // ceil(NN/256) scan blocks

typedef __attribute__((ext_vector_type(8))) short short8;
typedef __attribute__((ext_vector_type(4))) float f32x4;

__device__ __forceinline__ float bf2f(unsigned short u) {
    union { unsigned int i; float f; } c; c.i = ((unsigned int)u) << 16; return c.f;
}
__device__ __forceinline__ unsigned short f2bf(float f) {
    union { float f; unsigned int i; } c; c.f = f;
    unsigned int r = c.i + 0x7FFF + ((c.i >> 16) & 1);  // RNE
    return (unsigned short)(r >> 16);
}

// ---------------- prep: W->bf16, transposed [col][k], chunk-swizzled (cs = c ^ (col&7)) ----------------
// Layout: Wt[mat*16384 + col*128 + cs*8 + j] = W[k][col], where c = cs^(col&7), k = c*8+j.
// This makes the GEMM's LDS copy linear while ds_read_b128 fragments are bank-balanced.

__global__ void __launch_bounds__(256) prep_k(const float* __restrict__ W1, const float* __restrict__ Ws1,
                                              const float* __restrict__ W2, const float* __restrict__ Ws2,
                                              unsigned short* __restrict__ Wt, int* __restrict__ counts) {
    int idx = blockIdx.x * 256 + threadIdx.x;  // 0..65535
    int mat = idx >> 14;
    int p = idx & 16383;
    int col = p >> 7;
    int cs = (p >> 3) & 15;
    int j = p & 7;
    int c = cs ^ (col & 7);
    int k = c * 8 + j;
    const float* Wsrc = (mat == 0) ? W1 : (mat == 1) ? Ws1 : (mat == 2) ? W2 : Ws2;
    Wt[idx] = f2bf(Wsrc[k * DD + col]);
    if (idx < NN) counts[idx] = 1;
}

__global__ void __launch_bounds__(256) count_k(const int* __restrict__ dst, int* __restrict__ counts) {
    int e = blockIdx.x * 256 + threadIdx.x;
    if (e < NE) atomicAdd(&counts[dst[e]], 1);
}

// ---------------- two-level scan ----------------

__global__ void __launch_bounds__(256) partial_k(const int* __restrict__ counts, int* __restrict__ bsum) {
    __shared__ int tmp[256];
    int t = blockIdx.x * 256 + threadIdx.x;
    int v = (t < NN) ? counts[t] : 0;
    tmp[threadIdx.x] = v;
    __syncthreads();
    for (int off = 128; off > 0; off >>= 1) {
        if (threadIdx.x < off) tmp[threadIdx.x] += tmp[threadIdx.x + off];
        __syncthreads();
    }
    if (threadIdx.x == 0) bsum[blockIdx.x] = tmp[0];
}

__global__ void __launch_bounds__(256) scanb_k(const int* __restrict__ bsum, int* __restrict__ boff) {
    __shared__ int tmp[256];
    int tid = threadIdx.x;
    int v = (tid < NB) ? bsum[tid] : 0;
    tmp[tid] = v;
    __syncthreads();
    for (int off = 1; off < 256; off <<= 1) {
        int u = (tid >= off) ? tmp[tid - off] : 0;
        __syncthreads();
        tmp[tid] += u;
        __syncthreads();
    }
    if (tid < NB) boff[tid] = tmp[tid] - v;  // exclusive
}

// offsets + cursor + self-loop placement at the last slot of each segment
__global__ void __launch_bounds__(256) offsets_k(const int* __restrict__ counts, const int* __restrict__ boff,
                                                 int* __restrict__ offsets, int* __restrict__ cursor,
                                                 int* __restrict__ esrc) {
    __shared__ int tmp[256];
    int b = blockIdx.x, tid = threadIdx.x;
    int t = b * 256 + tid;
    int v = (t < NN) ? counts[t] : 0;
    tmp[tid] = v;
    __syncthreads();
    for (int off = 1; off < 256; off <<= 1) {
        int u = (tid >= off) ? tmp[tid - off] : 0;
        __syncthreads();
        tmp[tid] += u;
        __syncthreads();
    }
    if (t < NN) {
        int o = boff[b] + tmp[tid] - v;
        offsets[t] = o;
        cursor[t] = o;
        esrc[o + v - 1] = t;  // self loop in the reserved last slot
    }
    if (b == 0 && tid == 0) offsets[NN] = ET;
}

__global__ void __launch_bounds__(256) scatter_k(const int* __restrict__ src, const int* __restrict__ dst,
                                                 int* __restrict__ cursor, int* __restrict__ esrc) {
    int e = blockIdx.x * 256 + threadIdx.x;
    if (e < NE) {
        int pos = atomicAdd(&cursor[dst[e]], 1);
        esrc[pos] = src[e];
    }
}

// ---------------- MFMA dual GEMM + fused attention coefficients ----------------
// 64 rows/block, 4 waves; wave w: rows w*16..+15 x 128 cols (8 col-tiles).
// W + Wskip (64 KB, pre-swizzled) staged to LDS once per block; A-fragments read
// directly from global per-lane (each row belongs to exactly one lane).

template <bool F32IN>
__global__ void __launch_bounds__(256) gemm2_k(const void* __restrict__ xin,
                                               const unsigned short* __restrict__ Wl,  // W | Wskip contiguous
                                               const float* __restrict__ a_src, const float* __restrict__ a_dst,
                                               unsigned short* __restrict__ h2, unsigned short* __restrict__ skipb,
                                               float* __restrict__ nsrc, float* __restrict__ ndst) {
    __shared__ __align__(16) unsigned char wlds[65536];
    int row0 = blockIdx.x * 64;
    int tid = threadIdx.x;

    int w = tid >> 6, lidx = tid & 63;
    int lrow = lidx & 15, lk = lidx >> 4;
    int srow = row0 + w * 16 + lrow;
    int rclamp = srow < NN ? srow : NN - 1;

    // A-fragment prefetch (4 kc x 16B) — issued before staging stores for overlap
    short8 afrag[4];
    if (F32IN) {
        const float* xp = (const float*)xin + (size_t)rclamp * DD;
#pragma unroll
        for (int kc = 0; kc < 4; ++kc) {
            float4 u0 = *(const float4*)(xp + kc * 32 + lk * 8);
            float4 u1 = *(const float4*)(xp + kc * 32 + lk * 8 + 4);
            short8 a;
            a[0] = (short)f2bf(u0.x); a[1] = (short)f2bf(u0.y);
            a[2] = (short)f2bf(u0.z); a[3] = (short)f2bf(u0.w);
            a[4] = (short)f2bf(u1.x); a[5] = (short)f2bf(u1.y);
            a[6] = (short)f2bf(u1.z); a[7] = (short)f2bf(u1.w);
            afrag[kc] = a;
        }
    } else {
        const unsigned short* xp = (const unsigned short*)xin + (size_t)rclamp * DD;
#pragma unroll
        for (int kc = 0; kc < 4; ++kc)
            afrag[kc] = *(const short8*)(xp + kc * 32 + lk * 8);
    }

    // stage 64 KB W|Wskip, linear copy (global layout is pre-swizzled)
    {
        const uint4* g = (const uint4*)Wl;
        uint4* l = (uint4*)wlds;
#pragma unroll
        for (int i = 0; i < 16; ++i)
            l[i * 256 + tid] = g[i * 256 + tid];
    }
    __syncthreads();

    f32x4 zero = {0.f, 0.f, 0.f, 0.f};
    f32x4 acch[8], accs[8];
#pragma unroll
    for (int t = 0; t < 8; ++t) { acch[t] = zero; accs[t] = zero; }

#pragma unroll
    for (int kc = 0; kc < 4; ++kc) {
        short8 a = afrag[kc];
#pragma unroll
        for (int t = 0; t < 8; ++t) {
            int off = (t * 16 + lrow) * 256 + (((kc * 4 + lk) ^ (lrow & 7)) * 16);
            short8 b  = *(const short8*)&wlds[off];
            short8 bs = *(const short8*)&wlds[off + 32768];
            acch[t] = __builtin_amdgcn_mfma_f32_16x16x32_bf16(a, b, acch[t], 0, 0, 0);
            accs[t] = __builtin_amdgcn_mfma_f32_16x16x32_bf16(a, bs, accs[t], 0, 0, 0);
        }
    }

    // D: col = lane&15, row = (lane>>4)*4 + reg
#pragma unroll
    for (int t = 0; t < 8; ++t) {
#pragma unroll
        for (int q = 0; q < 4; ++q) {
            int grow = row0 + w * 16 + lk * 4 + q;
            if (grow < NN) {
                int col = t * 16 + lrow;
                h2[(size_t)grow * DD + col] = f2bf(acch[t][q]);
                skipb[(size_t)grow * DD + col] = f2bf(accs[t][q]);
            }
        }
    }

    // fused att: nsrc[row][h] = sum_c h[row][32h+c]*a_src[h][c]  (f32 accs, 16-lane reduce)
    float as_lo[NH], as_hi[NH], ad_lo[NH], ad_hi[NH];
#pragma unroll
    for (int h = 0; h < NH; ++h) {
        as_lo[h] = a_src[h * 32 + lrow];
        as_hi[h] = a_src[h * 32 + 16 + lrow];
        ad_lo[h] = a_dst[h * 32 + lrow];
        ad_hi[h] = a_dst[h * 32 + 16 + lrow];
    }
#pragma unroll
    for (int h = 0; h < NH; ++h) {
#pragma unroll
        for (int q = 0; q < 4; ++q) {
            float ps = acch[2 * h][q] * as_lo[h] + acch[2 * h + 1][q] * as_hi[h];
            float pd = acch[2 * h][q] * ad_lo[h] + acch[2 * h + 1][q] * ad_hi[h];
#pragma unroll
            for (int off = 1; off < 16; off <<= 1) {
                ps += __shfl_xor(ps, off);
                pd += __shfl_xor(pd, off);
            }
            if (lrow == 0) {
                int grow = row0 + w * 16 + lk * 4 + q;
                if (grow < NN) {
                    nsrc[grow * 4 + h] = ps;
                    ndst[grow * 4 + h] = pd;
                }
            }
        }
    }
}

// ---------------- aggregate: single-pass online segment softmax + weighted bf16 gather ----------------
// 4 nodes/block (1 wave each). Lane i: computes weight for (edge-slot i&15, head i>>4);
// owns output channels 2i, 2i+1 (head(2i)=i>>4, same lanes). 16 edges per chunk.

__global__ void __launch_bounds__(256) aggregate_k(const unsigned short* __restrict__ h2,
                                                   const unsigned short* __restrict__ skipb,
                                                   const float* __restrict__ nsrc, const float* __restrict__ ndst,
                                                   const int* __restrict__ offsets, const int* __restrict__ esrc,
                                                   const float* __restrict__ bias, float* __restrict__ outf,
                                                   unsigned short* __restrict__ outb) {
    int n = blockIdx.x * 4 + (threadIdx.x >> 6);
    int i = threadIdx.x & 63;
    int e = i & 15, hc = i >> 4;
    int gbase = i & 48;
    int beg = offsets[n], end = offsets[n + 1];
    float ad = ndst[n * 4 + hc];
    const unsigned int* h2w = (const unsigned int*)h2;

    float m = -1e30f, den = 0.f, acc0 = 0.f, acc1 = 0.f;
    for (int base = beg; base < end; base += 16) {
        int j = base + e;
        int jc = j < end ? j : end - 1;
        int s = esrc[jc];
        float a = nsrc[s * 4 + hc] + ad;
        a = a > 0.f ? a : NEG_SLOPE * a;
        if (j >= end) a = -1e30f;
        // chunk max per head (butterfly over edge-slot bits)
        float cm = a;
        cm = fmaxf(cm, __shfl_xor(cm, 1));
        cm = fmaxf(cm, __shfl_xor(cm, 2));
        cm = fmaxf(cm, __shfl_xor(cm, 4));
        cm = fmaxf(cm, __shfl_xor(cm, 8));
        float mn = fmaxf(m, cm);
        float scale = __expf(m - mn);   // first chunk: exp(-1e30-mn)=0
        float wgt = __expf(a - mn);     // masked lanes: 0
        m = mn;
        float sw = wgt;
        sw += __shfl_xor(sw, 1);
        sw += __shfl_xor(sw, 2);
        sw += __shfl_xor(sw, 4);
        sw += __shfl_xor(sw, 8);
        den = den * scale + sw;
        acc0 *= scale;
        acc1 *= scale;
#pragma unroll
        for (int e2 = 0; e2 < 16; ++e2) {
            int se = __shfl(s, e2);                 // lanes 0..15 hold s for slots 0..15
            float we = __shfl(wgt, gbase + e2);     // weight for (e2, my head)
            unsigned hv = h2w[se * 64 + i];         // 2 bf16 channels
            acc0 = fmaf(we, bf2f((unsigned short)(hv & 0xFFFF)), acc0);
            acc1 = fmaf(we, bf2f((unsigned short)(hv >> 16)), acc1);
        }
    }
    float inv = 1.f / (den + 1e-16f);
    int c0 = 2 * i;
    unsigned sk = ((const unsigned int*)skipb)[n * 64 + i];
    float2 bv = *(const float2*)&bias[c0];
    float o0 = acc0 * inv + bv.x + bf2f((unsigned short)(sk & 0xFFFF));
    float o1 = acc1 * inv + bv.y + bf2f((unsigned short)(sk >> 16));
    o0 = o0 > 0.f ? o0 : expm1f(o0);
    o1 = o1 > 0.f ? o1 : expm1f(o1);
    size_t o = (size_t)n * DD;
    if (outf) { outf[o + c0] = o0; outf[o + c0 + 1] = o1; }
    if (outb) { outb[o + c0] = f2bf(o0); outb[o + c0 + 1] = f2bf(o1); }
}

// ---------------- launch ----------------

extern "C" void kernel_launch(void* const* d_in, const int* in_sizes, int n_in,
                              void* d_out, int out_size, void* d_ws, size_t ws_size,
                              hipStream_t stream) {
    const float* x   = (const float*)d_in[0];
    const int* eidx  = (const int*)d_in[1];
    const float* W1  = (const float*)d_in[2];
    const float* as1 = (const float*)d_in[3];
    const float* ad1 = (const float*)d_in[4];
    const float* b1  = (const float*)d_in[5];
    const float* Ws1 = (const float*)d_in[6];
    const float* W2  = (const float*)d_in[7];
    const float* as2 = (const float*)d_in[8];
    const float* ad2 = (const float*)d_in[9];
    const float* b2  = (const float*)d_in[10];
    const float* Ws2 = (const float*)d_in[11];
    float* out = (float*)d_out;

    const int* e_src = eidx;
    const int* e_dst = eidx + NE;

    char* p = (char*)d_ws;
    unsigned short* h2    = (unsigned short*)p; p += (size_t)NN * DD * 2;
    unsigned short* xb    = (unsigned short*)p; p += (size_t)NN * DD * 2;
    unsigned short* skipb = (unsigned short*)p; p += (size_t)NN * DD * 2;
    float* nsrc = (float*)p; p += (size_t)NN * NH * 4;
    float* ndst = (float*)p; p += (size_t)NN * NH * 4;
    unsigned short* Wt = (unsigned short*)p; p += (size_t)4 * DD * DD * 2;
    int* counts  = (int*)p; p += (size_t)NN * 4;
    int* offsets = (int*)p; p += (size_t)(NN + 1) * 4;
    int* cursor  = (int*)p; p += (size_t)NN * 4;
    int* bsum    = (int*)p; p += 256 * 4;
    int* boff    = (int*)p; p += 256 * 4;
    int* esrc    = (int*)p; p += (size_t)ET * 4;

    // CSR build
    prep_k<<<256, 256, 0, stream>>>(W1, Ws1, W2, Ws2, Wt, counts);
    count_k<<<(NE + 255) / 256, 256, 0, stream>>>(e_dst, counts);
    partial_k<<<NB, 256, 0, stream>>>(counts, bsum);
    scanb_k<<<1, 256, 0, stream>>>(bsum, boff);
    offsets_k<<<NB, 256, 0, stream>>>(counts, boff, offsets, cursor, esrc);
    scatter_k<<<(NE + 255) / 256, 256, 0, stream>>>(e_src, e_dst, cursor, esrc);

    const int GG = (NN + 63) / 64;  // 782

    // layer 1
    gemm2_k<true><<<GG, 256, 0, stream>>>(x, Wt, as1, ad1, h2, skipb, nsrc, ndst);
    aggregate_k<<<NN / 4, 256, 0, stream>>>(h2, skipb, nsrc, ndst, offsets, esrc, b1, nullptr, xb);

    // layer 2
    gemm2_k<false><<<GG, 256, 0, stream>>>(xb, Wt + 32768, as2, ad2, h2, skipb, nsrc, ndst);
    aggregate_k<<<NN / 4, 256, 0, stream>>>(h2, skipb, nsrc, ndst, offsets, esrc, b2, out, nullptr);
}